// Round 3
// baseline (119.537 us; speedup 1.0000x reference)
//
#include <hip/hip_runtime.h>

// Problem constants (reference: B=32, L=64, C=4)
#define BB 32
#define LL 64
#define LC 256                 // L*C
#define NPAIR 2016             // L*(L-1)/2 pairs u<v
#define SPS 72                 // padded LDS stride for sp (breaks 128B bank wrap)
#define WSTRIDE 2048           // ws[b*WSTRIDE + pair]

// One block per pair t=(u,v), u<v. 256 threads = 32 b * 8 k.
// Cross-b theta3 row reuse: the 32 b's map onto <=16 rows (4 pu x 4 pv);
// same-row b's issue identical addresses -> L1 merge. Thread (b,k) walks
// w = v+1+k, +8, ... using sp[b][w] = 4w+c as the direct row offset.
__global__ __launch_bounds__(256) void pair_kernel(
    const float* __restrict__ x, const float* __restrict__ t2,
    const float* __restrict__ t3, float* __restrict__ ws)
{
    const int t = blockIdx.x;
    const int tid = threadIdx.x;

    // decode triangular index t = v*(v-1)/2 + u, 0 <= u < v < 64
    int v = (int)((1.0f + sqrtf(8.0f * (float)t + 1.0f)) * 0.5f);
    while (v * (v - 1) / 2 > t) --v;
    while ((v + 1) * v / 2 <= t) ++v;
    const int u = t - v * (v - 1) / 2;

    // recover one-hot codes for all (b,w): sp[b][w] = 4w + argmax_c x[b,w,c]
    __shared__ short sp[BB * SPS];
    {
        const float4* __restrict__ x4 = (const float4*)x;  // one float4 per (b,w)
#pragma unroll
        for (int i = 0; i < 8; ++i) {
            int idx = i * 256 + tid;          // = b*64 + w
            float4 f = x4[idx];
            int c = 0; float best = f.x;
            if (f.y > best) { best = f.y; c = 1; }
            if (f.z > best) { best = f.z; c = 2; }
            if (f.w > best) { best = f.w; c = 3; }
            sp[(idx >> 6) * SPS + (idx & 63)] = (short)(((idx & 63) << 2) | c);
        }
    }
    __syncthreads();

    const int b = tid >> 3, k = tid & 7;
    const short* __restrict__ spb = sp + b * SPS;
    const int pu = spb[u], pv = spb[v];
    const float* __restrict__ row = t3 + ((size_t)pu << 16) + ((size_t)pv << 8);

    float acc = 0.0f;
    for (int w = v + 1 + k; w < LL; w += 8)
        acc += row[spb[w]];

    // width-8 shuffle reduce over k
    acc += __shfl_down(acc, 4, 8);
    acc += __shfl_down(acc, 2, 8);
    acc += __shfl_down(acc, 1, 8);
    if (k == 0) ws[b * WSTRIDE + t] = acc + t2[pu * LC + pv];
}

// Fold 2016 partials per b + theta1 + theta0. 1024 threads = 32 b * 32 j.
__global__ __launch_bounds__(1024) void reduce_kernel(
    const float* __restrict__ x, const float* __restrict__ t0,
    const float* __restrict__ t1, const float* __restrict__ ws,
    float* __restrict__ out)
{
    const int tid = threadIdx.x;
    const int b = tid >> 5, j = tid & 31;
    const float* __restrict__ wsb = ws + b * WSTRIDE;
    float v = 0.0f;
    for (int t = j; t < NPAIR; t += 32) v += wsb[t];   // coalesced over j

    // order-1: each (b,j) covers w = j and w = j+32
    const float4* __restrict__ x4 = (const float4*)x;
#pragma unroll
    for (int i = 0; i < 2; ++i) {
        int w = j + i * 32;
        float4 f = x4[b * 64 + w];
        int c = 0; float best = f.x;
        if (f.y > best) { best = f.y; c = 1; }
        if (f.z > best) { best = f.z; c = 2; }
        if (f.w > best) { best = f.w; c = 3; }
        v += t1[(w << 2) | c];
    }

    for (int off = 16; off > 0; off >>= 1) v += __shfl_down(v, off, 32);
    if (j == 0) out[b] = v + t0[0];
}

extern "C" void kernel_launch(void* const* d_in, const int* in_sizes, int n_in,
                              void* d_out, int out_size, void* d_ws, size_t ws_size,
                              hipStream_t stream) {
    const float* x  = (const float*)d_in[0];  // (B, L*C)
    const float* t0 = (const float*)d_in[1];  // (1,)
    const float* t1 = (const float*)d_in[2];  // (L, C)
    const float* t2 = (const float*)d_in[3];  // (L, C, L, C)
    const float* t3 = (const float*)d_in[4];  // (L, C, L, C, L, C)
    float* out = (float*)d_out;               // (B, 1)
    float* ws = (float*)d_ws;                 // 32*2048 floats = 256 KB

    pair_kernel<<<NPAIR, 256, 0, stream>>>(x, t2, t3, ws);
    reduce_kernel<<<1, 1024, 0, stream>>>(x, t0, t1, ws, out);
}

// Round 5
// 104.669 us; speedup vs baseline: 1.1421x; 1.1421x over previous
//
#include <hip/hip_runtime.h>

// Problem constants (reference: B=32, L=64, C=4)
#define BB 32
#define LL 64
#define LC 256
#define NPAIR 2016
#define WSTRIDE 2048   // ws2[b][t] padded stride (floats)

// One block per pair t=(u,v), u<v. 256 threads = 32 b * 8 k.
// NO cross-kernel control data: every thread recomputes its one-hot codes
// from x (32 KB, L2-resident). Inner loop = dense float4 reads of the theta3
// row tail (address affine in m, no load in the address path) + register
// component-select. Cross-b reuse: 32 b's hit <=16 distinct theta3 rows.
__global__ __launch_bounds__(256) void pair_kernel(
    const float* __restrict__ x, const float* __restrict__ t2,
    const float* __restrict__ t3, float* __restrict__ ws2)
{
    const int t = blockIdx.x;
    // decode triangular index t = v*(v-1)/2 + u, 0 <= u < v < 64
    int v = (int)((1.0f + sqrtf(8.0f * (float)t + 1.0f)) * 0.5f);
    while (v * (v - 1) / 2 > t) --v;
    while ((v + 1) * v / 2 <= t) ++v;
    const int u = t - v * (v - 1) / 2;

    const int tid = threadIdx.x;
    const int b = tid >> 3, k = tid & 7;
    const float4* __restrict__ x4 = (const float4*)x + b * 64;  // one float4 per w

    // codes for my 8 w's (w = 8m + k), computed in registers
    int c[8];
#pragma unroll
    for (int m = 0; m < 8; ++m) {
        float4 f = x4[8 * m + k];
        int ci = 0; float best = f.x;
        if (f.y > best) { best = f.y; ci = 1; }
        if (f.z > best) { best = f.z; ci = 2; }
        if (f.w > best) { best = f.w; ci = 3; }
        c[m] = ci;
    }
    float4 fu = x4[u], fv = x4[v];
    int cu = 0; { float bst = fu.x;
        if (fu.y > bst) { bst = fu.y; cu = 1; }
        if (fu.z > bst) { bst = fu.z; cu = 2; }
        if (fu.w > bst) { bst = fu.w; cu = 3; } }
    int cv = 0; { float bst = fv.x;
        if (fv.y > bst) { bst = fv.y; cv = 1; }
        if (fv.z > bst) { bst = fv.z; cv = 2; }
        if (fv.w > bst) { bst = fv.w; cv = 3; } }
    const int pu = 4 * u + cu, pv = 4 * v + cv;

    const float4* __restrict__ row4 =
        (const float4*)(t3 + ((size_t)pu << 16) + ((size_t)pv << 8));

    float acc = 0.0f;
    const int mstart = (v + 1 - k + 7) >> 3;   // first m with 8m+k >= v+1
#pragma unroll
    for (int m = 0; m < 8; ++m) {
        if (m >= mstart) {
            float4 f = row4[8 * m + k];        // dense, affine address
            float s0 = (c[m] & 2) ? f.z : f.x;
            float s1 = (c[m] & 2) ? f.w : f.y;
            acc += (c[m] & 1) ? s1 : s0;
        }
    }
    // width-8 shuffle reduce over k
    acc += __shfl_down(acc, 4, 8);
    acc += __shfl_down(acc, 2, 8);
    acc += __shfl_down(acc, 1, 8);
    if (k == 0) ws2[b * WSTRIDE + t] = acc + t2[pu * LC + pv];
}

// One block per b: sum 2016 partials (coalesced) + theta1 (argmax recomputed
// from x — no control data crosses the kernel boundary) + theta0.
__global__ __launch_bounds__(256) void reduce_kernel(
    const float* __restrict__ x, const float* __restrict__ t0,
    const float* __restrict__ t1, const float* __restrict__ ws2,
    float* __restrict__ out)
{
    const int b = blockIdx.x;
    const int tid = threadIdx.x;
    const float* __restrict__ wsb = ws2 + b * WSTRIDE;
    float v = 0.0f;
    for (int t = tid; t < NPAIR; t += 256) v += wsb[t];  // coalesced
    if (tid < LL) {
        float4 f = ((const float4*)x)[b * 64 + tid];
        int c = 0; float best = f.x;
        if (f.y > best) { best = f.y; c = 1; }
        if (f.z > best) { best = f.z; c = 2; }
        if (f.w > best) { best = f.w; c = 3; }
        v += t1[4 * tid + c];
    }
    for (int off = 32; off > 0; off >>= 1) v += __shfl_down(v, off, 64);
    __shared__ float wsum[4];
    if ((tid & 63) == 0) wsum[tid >> 6] = v;
    __syncthreads();
    if (tid == 0) out[b] = wsum[0] + wsum[1] + wsum[2] + wsum[3] + t0[0];
}

extern "C" void kernel_launch(void* const* d_in, const int* in_sizes, int n_in,
                              void* d_out, int out_size, void* d_ws, size_t ws_size,
                              hipStream_t stream) {
    const float* x  = (const float*)d_in[0];  // (B, L*C)
    const float* t0 = (const float*)d_in[1];  // (1,)
    const float* t1 = (const float*)d_in[2];  // (L, C)
    const float* t2 = (const float*)d_in[3];  // (L, C, L, C)
    const float* t3 = (const float*)d_in[4];  // (L, C, L, C, L, C)
    float* out = (float*)d_out;               // (B, 1)
    float* ws2 = (float*)d_ws;                // 32*2048 floats = 256 KB

    pair_kernel<<<NPAIR, 256, 0, stream>>>(x, t2, t3, ws2);
    reduce_kernel<<<BB, 256, 0, stream>>>(x, t0, t1, ws2, out);
}